// Round 6
// baseline (752.743 us; speedup 1.0000x reference)
//
#include <hip/hip_runtime.h>
#include <cstdint>

// ---------------------------------------------------------------------------
// DirGraphSAGE round 5:
//  - k_agg4: column-QUARTERED aggregation (32 cols = 3.2MB slab fits 4MB
//    per-XCD L2; quarter = slowest grid dim so resident waves share one slab).
//    16 edges/wave-instr (4 lanes x uint4 per edge = one 64B line).
//  - k_gemm epilogue writes bf16 xbu directly for relu layers (l<2): the fp32
//    intermediate x1 and per-layer k_conv are gone (identical rounding).
//  - 3x k_wconv fused into one dispatch (gridDim.y=3).
//  - CSR build (rank-trick), multi-block scan unchanged.
// ---------------------------------------------------------------------------

typedef __bf16 bf16x8 __attribute__((ext_vector_type(8)));
typedef float f32x4 __attribute__((ext_vector_type(4)));

__device__ __forceinline__ unsigned short f2bf(float f) {
  unsigned u = __float_as_uint(f);
  u += 0x7FFFu + ((u >> 16) & 1u);   // round-to-nearest-even
  return (unsigned short)(u >> 16);
}
__device__ __forceinline__ float bflo(unsigned u) { return __uint_as_float(u << 16); }
__device__ __forceinline__ float bfhi(unsigned u) { return __uint_as_float(u & 0xFFFF0000u); }

__global__ __launch_bounds__(256) void k_degrees(const int* __restrict__ src,
                                                 const int* __restrict__ dst,
                                                 int* __restrict__ cnt_in,
                                                 int* __restrict__ cnt_out,
                                                 int* __restrict__ rankf,
                                                 int* __restrict__ rankb, int E) {
  int e = blockIdx.x * 256 + threadIdx.x;
  if (e >= E) return;
  int s = src[e], d = dst[e];
  rankf[e] = atomicAdd(&cnt_in[d], 1);   // rank within fwd list (grouped by dst)
  rankb[e] = atomicAdd(&cnt_out[s], 1);  // rank within bwd list (grouped by src)
}

__global__ __launch_bounds__(256) void k_inv(const int* __restrict__ cnt_in,
                                             const int* __restrict__ cnt_out,
                                             float* __restrict__ inv_in,
                                             float* __restrict__ inv_out, int n) {
  int i = blockIdx.x * 256 + threadIdx.x;
  if (i >= n) return;
  inv_out[i] = 1.0f / (float)max(cnt_out[i], 1);
  inv_in[i]  = 1.0f / (float)max(cnt_in[i], 1);
}

// --- 3-phase multi-block exclusive scan (CHUNK=2048/block, y-dim = which array)
__global__ __launch_bounds__(256) void k_scan_part(const int* __restrict__ cntA,
                                                   const int* __restrict__ cntB,
                                                   int* __restrict__ partA,
                                                   int* __restrict__ partB, int n) {
  const int* cnt = blockIdx.y ? cntB : cntA;
  int* part = blockIdx.y ? partB : partA;
  __shared__ int red[256];
  int t = threadIdx.x;
  int base = blockIdx.x * 2048 + t * 8;
  int s = 0;
#pragma unroll
  for (int i = 0; i < 8; ++i) {
    int idx = base + i;
    if (idx < n) s += cnt[idx];
  }
  red[t] = s;
  __syncthreads();
  for (int o = 128; o > 0; o >>= 1) {
    if (t < o) red[t] += red[t + o];
    __syncthreads();
  }
  if (t == 0) part[blockIdx.x] = red[0];
}

__global__ __launch_bounds__(64) void k_scan_tops(int* __restrict__ partA,
                                                  int* __restrict__ partB, int nb) {
  int* part = blockIdx.y ? partB : partA;
  if (threadIdx.x == 0) {
    int run = 0;
    for (int i = 0; i < nb; ++i) { int v = part[i]; part[i] = run; run += v; }
  }
}

__global__ __launch_bounds__(256) void k_scan_out(const int* __restrict__ cntA,
                                                  const int* __restrict__ cntB,
                                                  const int* __restrict__ partA,
                                                  const int* __restrict__ partB,
                                                  int* __restrict__ offA,
                                                  int* __restrict__ offB, int n) {
  const int* cnt = blockIdx.y ? cntB : cntA;
  const int* part = blockIdx.y ? partB : partA;
  int* off = blockIdx.y ? offB : offA;
  __shared__ int ts[256];
  int t = threadIdx.x;
  int base = blockIdx.x * 2048 + t * 8;
  int v[8];
  int s = 0;
#pragma unroll
  for (int i = 0; i < 8; ++i) {
    int idx = base + i;
    int c = (idx < n) ? cnt[idx] : 0;
    v[i] = s;          // exclusive prefix within thread
    s += c;
  }
  ts[t] = s;
  __syncthreads();
  for (int o = 1; o < 256; o <<= 1) {
    int val = (t >= o) ? ts[t - o] : 0;
    __syncthreads();
    ts[t] += val;
    __syncthreads();
  }
  int blockbase = part[blockIdx.x] + (t ? ts[t - 1] : 0);
#pragma unroll
  for (int i = 0; i < 8; ++i) {
    int idx = base + i;
    if (idx <= n) off[idx] = blockbase + v[i];   // idx==n writes the total
  }
}

// Atomic-free fill using precomputed ranks.
__global__ __launch_bounds__(256) void k_fill(const int* __restrict__ src,
                                              const int* __restrict__ dst,
                                              const int* __restrict__ offf,
                                              const int* __restrict__ offb,
                                              const int* __restrict__ rankf,
                                              const int* __restrict__ rankb,
                                              int* __restrict__ lstf,
                                              int* __restrict__ lstb, int E) {
  int e = blockIdx.x * 256 + threadIdx.x;
  if (e >= E) return;
  int s = src[e], d = dst[e];
  lstf[offf[d] + rankf[e]] = s;   // fwd: grouped by dst, holds src
  lstb[offb[s] + rankb[e]] = d;   // bwd: grouped by src, holds dst
}

// x (fp32, N x 128) -> xbu = bf16(x), packed bf16x2. (layer 0 only)
__global__ __launch_bounds__(256) void k_conv(const float* __restrict__ x,
                                              unsigned* __restrict__ xbu, int n) {
  int idx = blockIdx.x * 256 + threadIdx.x;  // over n*32 float4s
  if (idx >= n * 32) return;
  float4 xv = ((const float4*)x)[idx];
  unsigned u0 = (unsigned)f2bf(xv.x) | ((unsigned)f2bf(xv.y) << 16);
  unsigned u1 = (unsigned)f2bf(xv.z) | ((unsigned)f2bf(xv.w) << 16);
  ((uint2*)xbu)[idx] = make_uint2(u0, u1);
}

// W (fp32 384x128) -> Wt_hi, Wt_lo (bf16, 128x384, transposed, packed x2)
// All 3 layers in one dispatch (blockIdx.y selects layer).
__global__ __launch_bounds__(256) void k_wconv3(
    const float* __restrict__ Wa, const float* __restrict__ Wb,
    const float* __restrict__ Wc,
    unsigned* __restrict__ Ha, unsigned* __restrict__ Hb, unsigned* __restrict__ Hc,
    unsigned* __restrict__ La, unsigned* __restrict__ Lb, unsigned* __restrict__ Lc) {
  const float* W = (blockIdx.y == 0) ? Wa : ((blockIdx.y == 1) ? Wb : Wc);
  unsigned* Wth = (blockIdx.y == 0) ? Ha : ((blockIdx.y == 1) ? Hb : Hc);
  unsigned* Wtl = (blockIdx.y == 0) ? La : ((blockIdx.y == 1) ? Lb : Lc);
  int t = blockIdx.x * 256 + threadIdx.x;   // 128*192 threads; t = j*192 + k2
  if (t >= 128 * 192) return;
  int j = t / 192, k2 = t - j * 192;
  int k = k2 * 2;
  float w0 = W[k * 128 + j], w1 = W[(k + 1) * 128 + j];
  unsigned short h0 = f2bf(w0), h1 = f2bf(w1);
  float l0 = w0 - __uint_as_float((unsigned)h0 << 16);
  float l1 = w1 - __uint_as_float((unsigned)h1 << 16);
  Wth[t] = (unsigned)h0 | ((unsigned)h1 << 16);
  Wtl[t] = (unsigned)f2bf(l0) | ((unsigned)f2bf(l1) << 16);
}

// Column-quartered fused fwd+bwd aggregation.
// grid: x = node-blocks (4 waves/block = 4 nodes), y = dir (0 fwd, 1 bwd),
//       z = column quarter (slowest-varying => resident waves share one slab).
// Per wave: 16 edge slots x 4 lanes; each edge-lane-group reads one 64B line
// (uint4 = 8 bf16 cols of the 32-col quarter).
__global__ __launch_bounds__(256) void k_agg4(const uint4* __restrict__ xb,
                                              const int* __restrict__ offA,
                                              const int* __restrict__ lstA,
                                              const float* __restrict__ invA,
                                              const int* __restrict__ offB,
                                              const int* __restrict__ lstB,
                                              const float* __restrict__ invB,
                                              uint4* __restrict__ outA,
                                              uint4* __restrict__ outB, int n) {
  int node = (blockIdx.x * 256 + threadIdx.x) >> 6;
  if (node >= n) return;
  const int* off = blockIdx.y ? offB : offA;
  const int* lst = blockIdx.y ? lstB : lstA;
  const float* inv = blockIdx.y ? invB : invA;
  uint4* out = blockIdx.y ? outB : outA;
  int q = blockIdx.z;               // column quarter 0..3

  int lane = threadIdx.x & 63;
  int g = lane >> 2;                // edge slot 0..15
  int c = lane & 3;                 // uint4 within quarter (16B of 64B)
  int beg = off[node], end = off[node + 1];

  float acc[8];
#pragma unroll
  for (int k = 0; k < 8; ++k) acc[k] = 0.f;

  for (int i = beg; i < end; i += 16) {
    int e = i + g;
    if (e < end) {
      int u = lst[e];
      float w = inv[u];
      uint4 r = xb[(size_t)u * 16 + q * 4 + c];
      acc[0] = fmaf(bflo(r.x), w, acc[0]); acc[1] = fmaf(bfhi(r.x), w, acc[1]);
      acc[2] = fmaf(bflo(r.y), w, acc[2]); acc[3] = fmaf(bfhi(r.y), w, acc[3]);
      acc[4] = fmaf(bflo(r.z), w, acc[4]); acc[5] = fmaf(bfhi(r.z), w, acc[5]);
      acc[6] = fmaf(bflo(r.w), w, acc[6]); acc[7] = fmaf(bfhi(r.w), w, acc[7]);
    }
  }
  // reduce across the 16 edge slots (lane strides 4,8,16,32)
#pragma unroll
  for (int m = 4; m <= 32; m <<= 1)
#pragma unroll
    for (int k = 0; k < 8; ++k) acc[k] += __shfl_xor(acc[k], m, 64);
  if (g == 0) {
    uint4 o;
    o.x = (unsigned)f2bf(acc[0]) | ((unsigned)f2bf(acc[1]) << 16);
    o.y = (unsigned)f2bf(acc[2]) | ((unsigned)f2bf(acc[3]) << 16);
    o.z = (unsigned)f2bf(acc[4]) | ((unsigned)f2bf(acc[5]) << 16);
    o.w = (unsigned)f2bf(acc[6]) | ((unsigned)f2bf(acc[7]) << 16);
    out[(size_t)node * 16 + q * 4 + c] = o;
  }
}

// MFMA GEMM: h = bias + [xbu|fwdb|bwdb][v,:] @ (W_hi + W_lo)
// If outb != nullptr: write bf16(relu(h)) packed rows (next layer's xbu).
// Else: write fp32 h to outf (final layer, no relu).
// In-place safe for outb == xbu: block reads only rows [bm0,bm0+128) of xbu
// during staging (all kc), writes the same rows only in the epilogue.
__global__ __launch_bounds__(256) void k_gemm(const unsigned* __restrict__ xbu,
                                              const unsigned* __restrict__ fwdb,
                                              const unsigned* __restrict__ bwdb,
                                              const unsigned* __restrict__ Wth,
                                              const unsigned* __restrict__ Wtl,
                                              const float* __restrict__ bias,
                                              unsigned short* __restrict__ outb,
                                              float* __restrict__ outf, int n) {
  __shared__ uint4 sA[512];    // 8 KB: A chunk, frag order [mt][q][m]
  __shared__ uint4 sWh[512];   // 8 KB: W_hi chunk, frag order [nt][q][j&15]
  __shared__ uint4 sWl[512];   // 8 KB
  int tid = threadIdx.x;
  int bm0 = blockIdx.x * 128;
  int w = tid >> 6, lane = tid & 63;

  f32x4 acc[2][8];
#pragma unroll
  for (int mt = 0; mt < 2; ++mt)
#pragma unroll
    for (int nt = 0; nt < 8; ++nt) acc[mt][nt] = (f32x4){0.f, 0.f, 0.f, 0.f};

  const uint4* Wh4 = (const uint4*)Wth;   // row j: 48 uint4 (384 bf16)
  const uint4* Wl4 = (const uint4*)Wtl;

  for (int kc = 0; kc < 12; ++kc) {
    const uint4* src4 = (const uint4*)((kc < 4) ? xbu : ((kc < 8) ? fwdb : bwdb));
    int ko = (kc & 3) * 4;   // uint4 offset within row (16 uint4 = 128 bf16)
    __syncthreads();
#pragma unroll
    for (int p = 0; p < 2; ++p) {
      int f = tid + p * 256;          // 0..511
      int r = f >> 2, q = f & 3;      // r: row/col-of-W, q: k-quad
      int slot = (r >> 4) * 64 + q * 16 + (r & 15);
      int v = bm0 + r;
      uint4 val = make_uint4(0u, 0u, 0u, 0u);
      if (v < n) val = src4[(size_t)v * 16 + ko + q];
      sA[slot] = val;
      sWh[slot] = Wh4[(size_t)r * 48 + kc * 4 + q];
      sWl[slot] = Wl4[(size_t)r * 48 + kc * 4 + q];
    }
    __syncthreads();
    bf16x8 a0 = ((const bf16x8*)sA)[(2 * w) * 64 + lane];
    bf16x8 a1 = ((const bf16x8*)sA)[(2 * w + 1) * 64 + lane];
#pragma unroll
    for (int nt = 0; nt < 8; ++nt) {
      bf16x8 bh = ((const bf16x8*)sWh)[nt * 64 + lane];
      bf16x8 bl = ((const bf16x8*)sWl)[nt * 64 + lane];
      acc[0][nt] = __builtin_amdgcn_mfma_f32_16x16x32_bf16(a0, bh, acc[0][nt], 0, 0, 0);
      acc[0][nt] = __builtin_amdgcn_mfma_f32_16x16x32_bf16(a0, bl, acc[0][nt], 0, 0, 0);
      acc[1][nt] = __builtin_amdgcn_mfma_f32_16x16x32_bf16(a1, bh, acc[1][nt], 0, 0, 0);
      acc[1][nt] = __builtin_amdgcn_mfma_f32_16x16x32_bf16(a1, bl, acc[1][nt], 0, 0, 0);
    }
  }

  // Epilogue. C layout: col = lane&15, row = (lane>>4)*4 + reg  (m89-verified)
  int col = lane & 15;
  float bv[8];
#pragma unroll
  for (int nt = 0; nt < 8; ++nt) bv[nt] = bias[nt * 16 + col];
#pragma unroll
  for (int mt = 0; mt < 2; ++mt) {
    int rowbase = bm0 + w * 32 + mt * 16 + (lane >> 4) * 4;
#pragma unroll
    for (int reg = 0; reg < 4; ++reg) {
      int row = rowbase + reg;
      if (row >= n) continue;
      if (outb) {
#pragma unroll
        for (int nt = 0; nt < 8; ++nt) {
          float t = fmaxf(acc[mt][nt][reg] + bv[nt], 0.f);   // relu layers
          outb[(size_t)row * 128 + nt * 16 + col] = f2bf(t);
        }
      } else {
#pragma unroll
        for (int nt = 0; nt < 8; ++nt) {
          out:;
          float t = acc[mt][nt][reg] + bv[nt];
          outf[(size_t)row * 128 + nt * 16 + col] = t;
        }
      }
    }
  }
}

extern "C" void kernel_launch(void* const* d_in, const int* in_sizes, int n_in,
                              void* d_out, int out_size, void* d_ws, size_t ws_size,
                              hipStream_t stream) {
  const int D = 128;
  const int N = in_sizes[0] / D;
  const int E = in_sizes[7];

  const float* x  = (const float*)d_in[0];
  const float* W0 = (const float*)d_in[1];
  const float* b0 = (const float*)d_in[2];
  const float* W1 = (const float*)d_in[3];
  const float* b1 = (const float*)d_in[4];
  const float* W2 = (const float*)d_in[5];
  const float* b2 = (const float*)d_in[6];
  const int* src  = (const int*)d_in[7];
  const int* dst  = (const int*)d_in[8];
  float* out = (float*)d_out;

  char* p = (char*)d_ws;
  auto alloc = [&](size_t bytes) -> char* {
    char* r = p;
    p += (bytes + 15) & ~(size_t)15;
    return r;
  };
  float* invout = (float*)alloc((size_t)N * 4);
  float* invin  = (float*)alloc((size_t)N * 4);
  int* cntin  = (int*)alloc((size_t)N * 4);
  int* cntout = (int*)alloc((size_t)N * 4);
  int* offf = (int*)alloc((size_t)(N + 1) * 4);
  int* offb = (int*)alloc((size_t)(N + 1) * 4);
  int* rankf = (int*)alloc((size_t)E * 4);
  int* rankb = (int*)alloc((size_t)E * 4);
  int* lstf = (int*)alloc((size_t)E * 4);
  int* lstb = (int*)alloc((size_t)E * 4);
  unsigned* xbu = (unsigned*)alloc((size_t)N * 64 * 4);   // bf16x2 packed
  unsigned* fwdb = (unsigned*)alloc((size_t)N * 64 * 4);
  unsigned* bwdb = (unsigned*)alloc((size_t)N * 64 * 4);
  unsigned* Wth[3], *Wtl[3];
  for (int l = 0; l < 3; ++l) {
    Wth[l] = (unsigned*)alloc((size_t)128 * 192 * 4);
    Wtl[l] = (unsigned*)alloc((size_t)128 * 192 * 4);
  }
  int nbScan = (N + 1 + 2047) / 2048;
  int* partA = (int*)alloc((size_t)(nbScan + 1) * 4);
  int* partB = (int*)alloc((size_t)(nbScan + 1) * 4);

  hipMemsetAsync(cntin, 0, (size_t)2 * N * 4, stream);  // cntin+cntout contiguous

  k_degrees<<<(E + 255) / 256, 256, 0, stream>>>(src, dst, cntin, cntout, rankf,
                                                 rankb, E);
  k_inv<<<(N + 255) / 256, 256, 0, stream>>>(cntin, cntout, invin, invout, N);
  k_scan_part<<<dim3(nbScan, 2), 256, 0, stream>>>(cntin, cntout, partA, partB, N);
  k_scan_tops<<<dim3(1, 2), 64, 0, stream>>>(partA, partB, nbScan);
  k_scan_out<<<dim3(nbScan, 2), 256, 0, stream>>>(cntin, cntout, partA, partB,
                                                  offf, offb, N);
  k_fill<<<(E + 255) / 256, 256, 0, stream>>>(src, dst, offf, offb, rankf, rankb,
                                              lstf, lstb, E);
  k_wconv3<<<dim3((128 * 192 + 255) / 256, 3), 256, 0, stream>>>(
      W0, W1, W2, Wth[0], Wth[1], Wth[2], Wtl[0], Wtl[1], Wtl[2]);

  const float* bs[3] = {b0, b1, b2};
  int aggBlocks = (N * 64 + 255) / 256;   // 4 nodes/block; dir in y, quarter in z
  int convBlocks = (N * 32 + 255) / 256;
  int gemmBlocks = (N + 127) / 128;

  k_conv<<<convBlocks, 256, 0, stream>>>(x, xbu, N);   // layer-0 input only
  for (int l = 0; l < 3; ++l) {
    // fwd[v] = sum_{s:(s,v)} x[s]*inv_out[s]; bwd[v] = sum_{d:(v,d)} x[d]*inv_in[d]
    k_agg4<<<dim3(aggBlocks, 2, 4), 256, 0, stream>>>(
        (const uint4*)xbu, offf, lstf, invout, offb, lstb, invin,
        (uint4*)fwdb, (uint4*)bwdb, N);
    if (l < 2) {
      // writes bf16 relu output back into xbu (next layer's A input)
      k_gemm<<<gemmBlocks, 256, 0, stream>>>(xbu, fwdb, bwdb, Wth[l], Wtl[l],
                                             bs[l], (unsigned short*)xbu, nullptr, N);
    } else {
      k_gemm<<<gemmBlocks, 256, 0, stream>>>(xbu, fwdb, bwdb, Wth[l], Wtl[l],
                                             bs[l], nullptr, out, N);
    }
  }
}

// Round 7
// 677.562 us; speedup vs baseline: 1.1110x; 1.1110x over previous
//
#include <hip/hip_runtime.h>
#include <cstdint>

// ---------------------------------------------------------------------------
// DirGraphSAGE round 6:
//  - QUARTER-MAJOR feature layout [quarter][node][64B]: quarter q is a
//    CONTIGUOUS 3.2MB region -> fits 4MB per-XCD L2 -> gathers become L2 hits.
//    (r5's quartering failed because the quarter was address-interleaved:
//     421MB fetch = 100% miss. Slabs must be contiguous.)
//  - k_agg4 gathers 64B/edge from the active slab; dir=y, quarter=z (slowest).
//  - k_conv / k_gemm staging & epilogue adapted to quarter-major.
//  - CSR build, scan, split-W MFMA GEMM, bf16 epilogue chaining unchanged.
// ---------------------------------------------------------------------------

typedef __bf16 bf16x8 __attribute__((ext_vector_type(8)));
typedef float f32x4 __attribute__((ext_vector_type(4)));

__device__ __forceinline__ unsigned short f2bf(float f) {
  unsigned u = __float_as_uint(f);
  u += 0x7FFFu + ((u >> 16) & 1u);   // round-to-nearest-even
  return (unsigned short)(u >> 16);
}
__device__ __forceinline__ float bflo(unsigned u) { return __uint_as_float(u << 16); }
__device__ __forceinline__ float bfhi(unsigned u) { return __uint_as_float(u & 0xFFFF0000u); }

__global__ __launch_bounds__(256) void k_degrees(const int* __restrict__ src,
                                                 const int* __restrict__ dst,
                                                 int* __restrict__ cnt_in,
                                                 int* __restrict__ cnt_out,
                                                 int* __restrict__ rankf,
                                                 int* __restrict__ rankb, int E) {
  int e = blockIdx.x * 256 + threadIdx.x;
  if (e >= E) return;
  int s = src[e], d = dst[e];
  rankf[e] = atomicAdd(&cnt_in[d], 1);   // rank within fwd list (grouped by dst)
  rankb[e] = atomicAdd(&cnt_out[s], 1);  // rank within bwd list (grouped by src)
}

__global__ __launch_bounds__(256) void k_inv(const int* __restrict__ cnt_in,
                                             const int* __restrict__ cnt_out,
                                             float* __restrict__ inv_in,
                                             float* __restrict__ inv_out, int n) {
  int i = blockIdx.x * 256 + threadIdx.x;
  if (i >= n) return;
  inv_out[i] = 1.0f / (float)max(cnt_out[i], 1);
  inv_in[i]  = 1.0f / (float)max(cnt_in[i], 1);
}

// --- 3-phase multi-block exclusive scan (CHUNK=2048/block, y-dim = which array)
__global__ __launch_bounds__(256) void k_scan_part(const int* __restrict__ cntA,
                                                   const int* __restrict__ cntB,
                                                   int* __restrict__ partA,
                                                   int* __restrict__ partB, int n) {
  const int* cnt = blockIdx.y ? cntB : cntA;
  int* part = blockIdx.y ? partB : partA;
  __shared__ int red[256];
  int t = threadIdx.x;
  int base = blockIdx.x * 2048 + t * 8;
  int s = 0;
#pragma unroll
  for (int i = 0; i < 8; ++i) {
    int idx = base + i;
    if (idx < n) s += cnt[idx];
  }
  red[t] = s;
  __syncthreads();
  for (int o = 128; o > 0; o >>= 1) {
    if (t < o) red[t] += red[t + o];
    __syncthreads();
  }
  if (t == 0) part[blockIdx.x] = red[0];
}

__global__ __launch_bounds__(64) void k_scan_tops(int* __restrict__ partA,
                                                  int* __restrict__ partB, int nb) {
  int* part = blockIdx.y ? partB : partA;
  if (threadIdx.x == 0) {
    int run = 0;
    for (int i = 0; i < nb; ++i) { int v = part[i]; part[i] = run; run += v; }
  }
}

__global__ __launch_bounds__(256) void k_scan_out(const int* __restrict__ cntA,
                                                  const int* __restrict__ cntB,
                                                  const int* __restrict__ partA,
                                                  const int* __restrict__ partB,
                                                  int* __restrict__ offA,
                                                  int* __restrict__ offB, int n) {
  const int* cnt = blockIdx.y ? cntB : cntA;
  const int* part = blockIdx.y ? partB : partA;
  int* off = blockIdx.y ? offB : offA;
  __shared__ int ts[256];
  int t = threadIdx.x;
  int base = blockIdx.x * 2048 + t * 8;
  int v[8];
  int s = 0;
#pragma unroll
  for (int i = 0; i < 8; ++i) {
    int idx = base + i;
    int c = (idx < n) ? cnt[idx] : 0;
    v[i] = s;          // exclusive prefix within thread
    s += c;
  }
  ts[t] = s;
  __syncthreads();
  for (int o = 1; o < 256; o <<= 1) {
    int val = (t >= o) ? ts[t - o] : 0;
    __syncthreads();
    ts[t] += val;
    __syncthreads();
  }
  int blockbase = part[blockIdx.x] + (t ? ts[t - 1] : 0);
#pragma unroll
  for (int i = 0; i < 8; ++i) {
    int idx = base + i;
    if (idx <= n) off[idx] = blockbase + v[i];   // idx==n writes the total
  }
}

// Atomic-free fill using precomputed ranks.
__global__ __launch_bounds__(256) void k_fill(const int* __restrict__ src,
                                              const int* __restrict__ dst,
                                              const int* __restrict__ offf,
                                              const int* __restrict__ offb,
                                              const int* __restrict__ rankf,
                                              const int* __restrict__ rankb,
                                              int* __restrict__ lstf,
                                              int* __restrict__ lstb, int E) {
  int e = blockIdx.x * 256 + threadIdx.x;
  if (e >= E) return;
  int s = src[e], d = dst[e];
  lstf[offf[d] + rankf[e]] = s;   // fwd: grouped by dst, holds src
  lstb[offb[s] + rankb[e]] = d;   // bwd: grouped by src, holds dst
}

// x (fp32, N x 128) -> xbu quarter-major: uint2 layout [4][n][8]
__global__ __launch_bounds__(256) void k_conv(const float* __restrict__ x,
                                              unsigned* __restrict__ xbu, int n) {
  int idx = blockIdx.x * 256 + threadIdx.x;  // over n*32 float4s
  if (idx >= n * 32) return;
  int v = idx >> 5, w2 = idx & 31;           // w2: uint2 within row (32 per row)
  int q = w2 >> 3, c2 = w2 & 7;              // quarter, uint2 within quarter
  float4 xv = ((const float4*)x)[idx];
  unsigned u0 = (unsigned)f2bf(xv.x) | ((unsigned)f2bf(xv.y) << 16);
  unsigned u1 = (unsigned)f2bf(xv.z) | ((unsigned)f2bf(xv.w) << 16);
  ((uint2*)xbu)[(size_t)q * n * 8 + (size_t)v * 8 + c2] = make_uint2(u0, u1);
}

// W (fp32 384x128) -> Wt_hi, Wt_lo (bf16, 128x384, transposed, packed x2)
__global__ __launch_bounds__(256) void k_wconv3(
    const float* __restrict__ Wa, const float* __restrict__ Wb,
    const float* __restrict__ Wc,
    unsigned* __restrict__ Ha, unsigned* __restrict__ Hb, unsigned* __restrict__ Hc,
    unsigned* __restrict__ La, unsigned* __restrict__ Lb, unsigned* __restrict__ Lc) {
  const float* W = (blockIdx.y == 0) ? Wa : ((blockIdx.y == 1) ? Wb : Wc);
  unsigned* Wth = (blockIdx.y == 0) ? Ha : ((blockIdx.y == 1) ? Hb : Hc);
  unsigned* Wtl = (blockIdx.y == 0) ? La : ((blockIdx.y == 1) ? Lb : Lc);
  int t = blockIdx.x * 256 + threadIdx.x;   // 128*192 threads; t = j*192 + k2
  if (t >= 128 * 192) return;
  int j = t / 192, k2 = t - j * 192;
  int k = k2 * 2;
  float w0 = W[k * 128 + j], w1 = W[(k + 1) * 128 + j];
  unsigned short h0 = f2bf(w0), h1 = f2bf(w1);
  float l0 = w0 - __uint_as_float((unsigned)h0 << 16);
  float l1 = w1 - __uint_as_float((unsigned)h1 << 16);
  Wth[t] = (unsigned)h0 | ((unsigned)h1 << 16);
  Wtl[t] = (unsigned)f2bf(l0) | ((unsigned)f2bf(l1) << 16);
}

// Quarter-major fused fwd+bwd aggregation.
// grid: x = node-blocks (4 nodes/block), y = dir, z = quarter (slowest).
// Slab q is contiguous 3.2MB: xb4[q*n*4 + u*4 + c], c in [0,4) uint4s.
// 16 edge slots x 4 lanes; one 64B line per edge.
__global__ __launch_bounds__(256) void k_agg4(const uint4* __restrict__ xb,
                                              const int* __restrict__ offA,
                                              const int* __restrict__ lstA,
                                              const float* __restrict__ invA,
                                              const int* __restrict__ offB,
                                              const int* __restrict__ lstB,
                                              const float* __restrict__ invB,
                                              uint4* __restrict__ outA,
                                              uint4* __restrict__ outB, int n) {
  int node = (blockIdx.x * 256 + threadIdx.x) >> 6;
  if (node >= n) return;
  const int* off = blockIdx.y ? offB : offA;
  const int* lst = blockIdx.y ? lstB : lstA;
  const float* inv = blockIdx.y ? invB : invA;
  uint4* out = blockIdx.y ? outB : outA;
  size_t slab = (size_t)blockIdx.z * n * 4;   // quarter slab base (uint4 units)

  int lane = threadIdx.x & 63;
  int g = lane >> 2;                // edge slot 0..15
  int c = lane & 3;                 // uint4 within 64B quarter row
  int beg = off[node], end = off[node + 1];

  float acc[8];
#pragma unroll
  for (int k = 0; k < 8; ++k) acc[k] = 0.f;

  for (int i = beg; i < end; i += 16) {
    int e = i + g;
    if (e < end) {
      int u = lst[e];
      float w = inv[u];
      uint4 r = xb[slab + (size_t)u * 4 + c];
      acc[0] = fmaf(bflo(r.x), w, acc[0]); acc[1] = fmaf(bfhi(r.x), w, acc[1]);
      acc[2] = fmaf(bflo(r.y), w, acc[2]); acc[3] = fmaf(bfhi(r.y), w, acc[3]);
      acc[4] = fmaf(bflo(r.z), w, acc[4]); acc[5] = fmaf(bfhi(r.z), w, acc[5]);
      acc[6] = fmaf(bflo(r.w), w, acc[6]); acc[7] = fmaf(bfhi(r.w), w, acc[7]);
    }
  }
#pragma unroll
  for (int m = 4; m <= 32; m <<= 1)
#pragma unroll
    for (int k = 0; k < 8; ++k) acc[k] += __shfl_xor(acc[k], m, 64);
  if (g == 0) {
    uint4 o;
    o.x = (unsigned)f2bf(acc[0]) | ((unsigned)f2bf(acc[1]) << 16);
    o.y = (unsigned)f2bf(acc[2]) | ((unsigned)f2bf(acc[3]) << 16);
    o.z = (unsigned)f2bf(acc[4]) | ((unsigned)f2bf(acc[5]) << 16);
    o.w = (unsigned)f2bf(acc[6]) | ((unsigned)f2bf(acc[7]) << 16);
    out[slab + (size_t)node * 4 + c] = o;
  }
}

// MFMA GEMM: h = bias + [xbu|fwdb|bwdb][v,:] @ (W_hi + W_lo)
// A operands are quarter-major [4][n][4 uint4]; chunk kc uses slab kc&3.
// If outb: write bf16(relu(h)) quarter-major (next layer's xbu). Else fp32 outf.
__global__ __launch_bounds__(256) void k_gemm(const unsigned* __restrict__ xbu,
                                              const unsigned* __restrict__ fwdb,
                                              const unsigned* __restrict__ bwdb,
                                              const unsigned* __restrict__ Wth,
                                              const unsigned* __restrict__ Wtl,
                                              const float* __restrict__ bias,
                                              unsigned short* __restrict__ outb,
                                              float* __restrict__ outf, int n) {
  __shared__ uint4 sA[512];    // 8 KB: A chunk, frag order [mt][q][m]
  __shared__ uint4 sWh[512];   // 8 KB
  __shared__ uint4 sWl[512];   // 8 KB
  int tid = threadIdx.x;
  int bm0 = blockIdx.x * 128;
  int w = tid >> 6, lane = tid & 63;
  size_t n4 = (size_t)n * 4;

  f32x4 acc[2][8];
#pragma unroll
  for (int mt = 0; mt < 2; ++mt)
#pragma unroll
    for (int nt = 0; nt < 8; ++nt) acc[mt][nt] = (f32x4){0.f, 0.f, 0.f, 0.f};

  const uint4* Wh4 = (const uint4*)Wth;   // row j: 48 uint4 (384 bf16)
  const uint4* Wl4 = (const uint4*)Wtl;

  for (int kc = 0; kc < 12; ++kc) {
    const uint4* src4 = (const uint4*)((kc < 4) ? xbu : ((kc < 8) ? fwdb : bwdb));
    size_t slab = (size_t)(kc & 3) * n4;
    __syncthreads();
#pragma unroll
    for (int p = 0; p < 2; ++p) {
      int f = tid + p * 256;          // 0..511
      int r = f >> 2, q = f & 3;      // r: row/col-of-W, q: k-quad (uint4 in slab row)
      int slot = (r >> 4) * 64 + q * 16 + (r & 15);
      int v = bm0 + r;
      uint4 val = make_uint4(0u, 0u, 0u, 0u);
      if (v < n) val = src4[slab + (size_t)v * 4 + q];
      sA[slot] = val;
      sWh[slot] = Wh4[(size_t)r * 48 + kc * 4 + q];
      sWl[slot] = Wl4[(size_t)r * 48 + kc * 4 + q];
    }
    __syncthreads();
    bf16x8 a0 = ((const bf16x8*)sA)[(2 * w) * 64 + lane];
    bf16x8 a1 = ((const bf16x8*)sA)[(2 * w + 1) * 64 + lane];
#pragma unroll
    for (int nt = 0; nt < 8; ++nt) {
      bf16x8 bh = ((const bf16x8*)sWh)[nt * 64 + lane];
      bf16x8 bl = ((const bf16x8*)sWl)[nt * 64 + lane];
      acc[0][nt] = __builtin_amdgcn_mfma_f32_16x16x32_bf16(a0, bh, acc[0][nt], 0, 0, 0);
      acc[0][nt] = __builtin_amdgcn_mfma_f32_16x16x32_bf16(a0, bl, acc[0][nt], 0, 0, 0);
      acc[1][nt] = __builtin_amdgcn_mfma_f32_16x16x32_bf16(a1, bh, acc[1][nt], 0, 0, 0);
      acc[1][nt] = __builtin_amdgcn_mfma_f32_16x16x32_bf16(a1, bl, acc[1][nt], 0, 0, 0);
    }
  }

  // Epilogue. C layout: col = lane&15, row = (lane>>4)*4 + reg  (m89-verified)
  int col = lane & 15;
  float bv[8];
#pragma unroll
  for (int nt = 0; nt < 8; ++nt) bv[nt] = bias[nt * 16 + col];
#pragma unroll
  for (int mt = 0; mt < 2; ++mt) {
    int rowbase = bm0 + w * 32 + mt * 16 + (lane >> 4) * 4;
#pragma unroll
    for (int reg = 0; reg < 4; ++reg) {
      int row = rowbase + reg;
      if (row >= n) continue;
      if (outb) {
        // quarter-major bf16: element j = nt*16+col; quarter = nt>>1
#pragma unroll
        for (int nt = 0; nt < 8; ++nt) {
          float t = fmaxf(acc[mt][nt][reg] + bv[nt], 0.f);   // relu layers
          size_t addr = (size_t)(nt >> 1) * n * 32 + (size_t)row * 32 +
                        (nt & 1) * 16 + col;
          outb[addr] = f2bf(t);
        }
      } else {
#pragma unroll
        for (int nt = 0; nt < 8; ++nt) {
          float t = acc[mt][nt][reg] + bv[nt];
          outf[(size_t)row * 128 + nt * 16 + col] = t;
        }
      }
    }
  }
}

extern "C" void kernel_launch(void* const* d_in, const int* in_sizes, int n_in,
                              void* d_out, int out_size, void* d_ws, size_t ws_size,
                              hipStream_t stream) {
  const int D = 128;
  const int N = in_sizes[0] / D;
  const int E = in_sizes[7];

  const float* x  = (const float*)d_in[0];
  const float* W0 = (const float*)d_in[1];
  const float* b0 = (const float*)d_in[2];
  const float* W1 = (const float*)d_in[3];
  const float* b1 = (const float*)d_in[4];
  const float* W2 = (const float*)d_in[5];
  const float* b2 = (const float*)d_in[6];
  const int* src  = (const int*)d_in[7];
  const int* dst  = (const int*)d_in[8];
  float* out = (float*)d_out;

  char* p = (char*)d_ws;
  auto alloc = [&](size_t bytes) -> char* {
    char* r = p;
    p += (bytes + 15) & ~(size_t)15;
    return r;
  };
  float* invout = (float*)alloc((size_t)N * 4);
  float* invin  = (float*)alloc((size_t)N * 4);
  int* cntin  = (int*)alloc((size_t)N * 4);
  int* cntout = (int*)alloc((size_t)N * 4);
  int* offf = (int*)alloc((size_t)(N + 1) * 4);
  int* offb = (int*)alloc((size_t)(N + 1) * 4);
  int* rankf = (int*)alloc((size_t)E * 4);
  int* rankb = (int*)alloc((size_t)E * 4);
  int* lstf = (int*)alloc((size_t)E * 4);
  int* lstb = (int*)alloc((size_t)E * 4);
  unsigned* xbu = (unsigned*)alloc((size_t)N * 64 * 4);   // quarter-major bf16x2
  unsigned* fwdb = (unsigned*)alloc((size_t)N * 64 * 4);
  unsigned* bwdb = (unsigned*)alloc((size_t)N * 64 * 4);
  unsigned* Wth[3], *Wtl[3];
  for (int l = 0; l < 3; ++l) {
    Wth[l] = (unsigned*)alloc((size_t)128 * 192 * 4);
    Wtl[l] = (unsigned*)alloc((size_t)128 * 192 * 4);
  }
  int nbScan = (N + 1 + 2047) / 2048;
  int* partA = (int*)alloc((size_t)(nbScan + 1) * 4);
  int* partB = (int*)alloc((size_t)(nbScan + 1) * 4);

  hipMemsetAsync(cntin, 0, (size_t)2 * N * 4, stream);  // cntin+cntout contiguous

  k_degrees<<<(E + 255) / 256, 256, 0, stream>>>(src, dst, cntin, cntout, rankf,
                                                 rankb, E);
  k_inv<<<(N + 255) / 256, 256, 0, stream>>>(cntin, cntout, invin, invout, N);
  k_scan_part<<<dim3(nbScan, 2), 256, 0, stream>>>(cntin, cntout, partA, partB, N);
  k_scan_tops<<<dim3(1, 2), 64, 0, stream>>>(partA, partB, nbScan);
  k_scan_out<<<dim3(nbScan, 2), 256, 0, stream>>>(cntin, cntout, partA, partB,
                                                  offf, offb, N);
  k_fill<<<(E + 255) / 256, 256, 0, stream>>>(src, dst, offf, offb, rankf, rankb,
                                              lstf, lstb, E);
  k_wconv3<<<dim3((128 * 192 + 255) / 256, 3), 256, 0, stream>>>(
      W0, W1, W2, Wth[0], Wth[1], Wth[2], Wtl[0], Wtl[1], Wtl[2]);

  const float* bs[3] = {b0, b1, b2};
  int aggBlocks = (N * 64 + 255) / 256;   // 4 nodes/block; dir in y, quarter in z
  int convBlocks = (N * 32 + 255) / 256;
  int gemmBlocks = (N + 127) / 128;

  k_conv<<<convBlocks, 256, 0, stream>>>(x, xbu, N);   // layer-0 input only
  for (int l = 0; l < 3; ++l) {
    k_agg4<<<dim3(aggBlocks, 2, 4), 256, 0, stream>>>(
        (const uint4*)xbu, offf, lstf, invout, offb, lstb, invin,
        (uint4*)fwdb, (uint4*)bwdb, N);
    if (l < 2) {
      k_gemm<<<gemmBlocks, 256, 0, stream>>>(xbu, fwdb, bwdb, Wth[l], Wtl[l],
                                             bs[l], (unsigned short*)xbu, nullptr, N);
    } else {
      k_gemm<<<gemmBlocks, 256, 0, stream>>>(xbu, fwdb, bwdb, Wth[l], Wtl[l],
                                             bs[l], nullptr, out, N);
    }
  }
}

// Round 8
// 563.828 us; speedup vs baseline: 1.3351x; 1.2017x over previous
//
#include <hip/hip_runtime.h>
#include <cstdint>

// ---------------------------------------------------------------------------
// DirGraphSAGE round 7:
//  - k_agg5: 4 lanes/node, 16 nodes/wave (mean degree = 16 made r6's
//    wave-per-node epilogue dominate: VALUBusy 62%). Private per-lane
//    accumulators -> NO shuffles; coalesced 1KB wave store.
//  - edge payload (u, inv[u]) pre-fused in k_fill: dependent-load chain
//    depth 2 -> 1; unroll x2 for two independent gather chains.
//  - quarter-major contiguous slabs kept (r6 win: FETCH 422->97MB).
//  - CSR build, scan, split-W MFMA GEMM, bf16 epilogue chaining unchanged.
// ---------------------------------------------------------------------------

typedef __bf16 bf16x8 __attribute__((ext_vector_type(8)));
typedef float f32x4 __attribute__((ext_vector_type(4)));

__device__ __forceinline__ unsigned short f2bf(float f) {
  unsigned u = __float_as_uint(f);
  u += 0x7FFFu + ((u >> 16) & 1u);   // round-to-nearest-even
  return (unsigned short)(u >> 16);
}
__device__ __forceinline__ float bflo(unsigned u) { return __uint_as_float(u << 16); }
__device__ __forceinline__ float bfhi(unsigned u) { return __uint_as_float(u & 0xFFFF0000u); }

__global__ __launch_bounds__(256) void k_degrees(const int* __restrict__ src,
                                                 const int* __restrict__ dst,
                                                 int* __restrict__ cnt_in,
                                                 int* __restrict__ cnt_out,
                                                 int* __restrict__ rankf,
                                                 int* __restrict__ rankb, int E) {
  int e = blockIdx.x * 256 + threadIdx.x;
  if (e >= E) return;
  int s = src[e], d = dst[e];
  rankf[e] = atomicAdd(&cnt_in[d], 1);   // rank within fwd list (grouped by dst)
  rankb[e] = atomicAdd(&cnt_out[s], 1);  // rank within bwd list (grouped by src)
}

__global__ __launch_bounds__(256) void k_inv(const int* __restrict__ cnt_in,
                                             const int* __restrict__ cnt_out,
                                             float* __restrict__ inv_in,
                                             float* __restrict__ inv_out, int n) {
  int i = blockIdx.x * 256 + threadIdx.x;
  if (i >= n) return;
  inv_out[i] = 1.0f / (float)max(cnt_out[i], 1);
  inv_in[i]  = 1.0f / (float)max(cnt_in[i], 1);
}

// --- 3-phase multi-block exclusive scan (CHUNK=2048/block, y-dim = which array)
__global__ __launch_bounds__(256) void k_scan_part(const int* __restrict__ cntA,
                                                   const int* __restrict__ cntB,
                                                   int* __restrict__ partA,
                                                   int* __restrict__ partB, int n) {
  const int* cnt = blockIdx.y ? cntB : cntA;
  int* part = blockIdx.y ? partB : partA;
  __shared__ int red[256];
  int t = threadIdx.x;
  int base = blockIdx.x * 2048 + t * 8;
  int s = 0;
#pragma unroll
  for (int i = 0; i < 8; ++i) {
    int idx = base + i;
    if (idx < n) s += cnt[idx];
  }
  red[t] = s;
  __syncthreads();
  for (int o = 128; o > 0; o >>= 1) {
    if (t < o) red[t] += red[t + o];
    __syncthreads();
  }
  if (t == 0) part[blockIdx.x] = red[0];
}

__global__ __launch_bounds__(64) void k_scan_tops(int* __restrict__ partA,
                                                  int* __restrict__ partB, int nb) {
  int* part = blockIdx.y ? partB : partA;
  if (threadIdx.x == 0) {
    int run = 0;
    for (int i = 0; i < nb; ++i) { int v = part[i]; part[i] = run; run += v; }
  }
}

__global__ __launch_bounds__(256) void k_scan_out(const int* __restrict__ cntA,
                                                  const int* __restrict__ cntB,
                                                  const int* __restrict__ partA,
                                                  const int* __restrict__ partB,
                                                  int* __restrict__ offA,
                                                  int* __restrict__ offB, int n) {
  const int* cnt = blockIdx.y ? cntB : cntA;
  const int* part = blockIdx.y ? partB : partA;
  int* off = blockIdx.y ? offB : offA;
  __shared__ int ts[256];
  int t = threadIdx.x;
  int base = blockIdx.x * 2048 + t * 8;
  int v[8];
  int s = 0;
#pragma unroll
  for (int i = 0; i < 8; ++i) {
    int idx = base + i;
    int c = (idx < n) ? cnt[idx] : 0;
    v[i] = s;          // exclusive prefix within thread
    s += c;
  }
  ts[t] = s;
  __syncthreads();
  for (int o = 1; o < 256; o <<= 1) {
    int val = (t >= o) ? ts[t - o] : 0;
    __syncthreads();
    ts[t] += val;
    __syncthreads();
  }
  int blockbase = part[blockIdx.x] + (t ? ts[t - 1] : 0);
#pragma unroll
  for (int i = 0; i < 8; ++i) {
    int idx = base + i;
    if (idx <= n) off[idx] = blockbase + v[i];   // idx==n writes the total
  }
}

// Atomic-free fill; writes fused edge payload (u, inv[u]).
__global__ __launch_bounds__(256) void k_fill(const int* __restrict__ src,
                                              const int* __restrict__ dst,
                                              const int* __restrict__ offf,
                                              const int* __restrict__ offb,
                                              const int* __restrict__ rankf,
                                              const int* __restrict__ rankb,
                                              const float* __restrict__ invout,
                                              const float* __restrict__ invin,
                                              uint2* __restrict__ epf,
                                              uint2* __restrict__ epb, int E) {
  int e = blockIdx.x * 256 + threadIdx.x;
  if (e >= E) return;
  int s = src[e], d = dst[e];
  // fwd: grouped by dst, payload = (src, inv_out[src])
  epf[offf[d] + rankf[e]] = make_uint2((unsigned)s, __float_as_uint(invout[s]));
  // bwd: grouped by src, payload = (dst, inv_in[dst])
  epb[offb[s] + rankb[e]] = make_uint2((unsigned)d, __float_as_uint(invin[d]));
}

// x (fp32, N x 128) -> xbu quarter-major: uint2 layout [4][n][8]
__global__ __launch_bounds__(256) void k_conv(const float* __restrict__ x,
                                              unsigned* __restrict__ xbu, int n) {
  int idx = blockIdx.x * 256 + threadIdx.x;  // over n*32 float4s
  if (idx >= n * 32) return;
  int v = idx >> 5, w2 = idx & 31;           // w2: uint2 within row (32 per row)
  int q = w2 >> 3, c2 = w2 & 7;              // quarter, uint2 within quarter
  float4 xv = ((const float4*)x)[idx];
  unsigned u0 = (unsigned)f2bf(xv.x) | ((unsigned)f2bf(xv.y) << 16);
  unsigned u1 = (unsigned)f2bf(xv.z) | ((unsigned)f2bf(xv.w) << 16);
  ((uint2*)xbu)[(size_t)q * n * 8 + (size_t)v * 8 + c2] = make_uint2(u0, u1);
}

// W (fp32 384x128) -> Wt_hi, Wt_lo (bf16, 128x384, transposed, packed x2)
__global__ __launch_bounds__(256) void k_wconv3(
    const float* __restrict__ Wa, const float* __restrict__ Wb,
    const float* __restrict__ Wc,
    unsigned* __restrict__ Ha, unsigned* __restrict__ Hb, unsigned* __restrict__ Hc,
    unsigned* __restrict__ La, unsigned* __restrict__ Lb, unsigned* __restrict__ Lc) {
  const float* W = (blockIdx.y == 0) ? Wa : ((blockIdx.y == 1) ? Wb : Wc);
  unsigned* Wth = (blockIdx.y == 0) ? Ha : ((blockIdx.y == 1) ? Hb : Hc);
  unsigned* Wtl = (blockIdx.y == 0) ? La : ((blockIdx.y == 1) ? Lb : Lc);
  int t = blockIdx.x * 256 + threadIdx.x;   // 128*192 threads; t = j*192 + k2
  if (t >= 128 * 192) return;
  int j = t / 192, k2 = t - j * 192;
  int k = k2 * 2;
  float w0 = W[k * 128 + j], w1 = W[(k + 1) * 128 + j];
  unsigned short h0 = f2bf(w0), h1 = f2bf(w1);
  float l0 = w0 - __uint_as_float((unsigned)h0 << 16);
  float l1 = w1 - __uint_as_float((unsigned)h1 << 16);
  Wth[t] = (unsigned)h0 | ((unsigned)h1 << 16);
  Wtl[t] = (unsigned)f2bf(l0) | ((unsigned)f2bf(l1) << 16);
}

// Quarter-major aggregation, 4 lanes/node (16 nodes/wave), no shuffles.
// grid: x = node blocks (64 nodes/block), y = dir, z = quarter (slowest).
// Lane (gi,c): node = wave*16+gi, accumulates uint4 column-chunk c privately.
__global__ __launch_bounds__(256) void k_agg5(const uint4* __restrict__ xb,
                                              const int* __restrict__ offA,
                                              const uint2* __restrict__ epA,
                                              const int* __restrict__ offB,
                                              const uint2* __restrict__ epB,
                                              uint4* __restrict__ outA,
                                              uint4* __restrict__ outB, int n) {
  int wid = (blockIdx.x * 256 + threadIdx.x) >> 6;
  int lane = threadIdx.x & 63;
  int gi = lane >> 2, c = lane & 3;
  int node = wid * 16 + gi;
  if (node >= n) return;
  const int* off = blockIdx.y ? offB : offA;
  const uint2* ep = blockIdx.y ? epB : epA;
  uint4* out = blockIdx.y ? outB : outA;
  size_t slab = (size_t)blockIdx.z * n * 4;   // quarter slab base (uint4 units)

  int i = off[node], end = off[node + 1];
  float acc[8];
#pragma unroll
  for (int k = 0; k < 8; ++k) acc[k] = 0.f;

  for (; i + 1 < end; i += 2) {
    uint2 e0 = ep[i], e1 = ep[i + 1];
    uint4 r0 = xb[slab + (size_t)e0.x * 4 + c];
    uint4 r1 = xb[slab + (size_t)e1.x * 4 + c];
    float w0 = __uint_as_float(e0.y), w1 = __uint_as_float(e1.y);
    acc[0] = fmaf(bflo(r0.x), w0, acc[0]); acc[1] = fmaf(bfhi(r0.x), w0, acc[1]);
    acc[2] = fmaf(bflo(r0.y), w0, acc[2]); acc[3] = fmaf(bfhi(r0.y), w0, acc[3]);
    acc[4] = fmaf(bflo(r0.z), w0, acc[4]); acc[5] = fmaf(bfhi(r0.z), w0, acc[5]);
    acc[6] = fmaf(bflo(r0.w), w0, acc[6]); acc[7] = fmaf(bfhi(r0.w), w0, acc[7]);
    acc[0] = fmaf(bflo(r1.x), w1, acc[0]); acc[1] = fmaf(bfhi(r1.x), w1, acc[1]);
    acc[2] = fmaf(bflo(r1.y), w1, acc[2]); acc[3] = fmaf(bfhi(r1.y), w1, acc[3]);
    acc[4] = fmaf(bflo(r1.z), w1, acc[4]); acc[5] = fmaf(bfhi(r1.z), w1, acc[5]);
    acc[6] = fmaf(bflo(r1.w), w1, acc[6]); acc[7] = fmaf(bfhi(r1.w), w1, acc[7]);
  }
  if (i < end) {
    uint2 e0 = ep[i];
    uint4 r0 = xb[slab + (size_t)e0.x * 4 + c];
    float w0 = __uint_as_float(e0.y);
    acc[0] = fmaf(bflo(r0.x), w0, acc[0]); acc[1] = fmaf(bfhi(r0.x), w0, acc[1]);
    acc[2] = fmaf(bflo(r0.y), w0, acc[2]); acc[3] = fmaf(bfhi(r0.y), w0, acc[3]);
    acc[4] = fmaf(bflo(r0.z), w0, acc[4]); acc[5] = fmaf(bfhi(r0.z), w0, acc[5]);
    acc[6] = fmaf(bflo(r0.w), w0, acc[6]); acc[7] = fmaf(bfhi(r0.w), w0, acc[7]);
  }

  uint4 o;
  o.x = (unsigned)f2bf(acc[0]) | ((unsigned)f2bf(acc[1]) << 16);
  o.y = (unsigned)f2bf(acc[2]) | ((unsigned)f2bf(acc[3]) << 16);
  o.z = (unsigned)f2bf(acc[4]) | ((unsigned)f2bf(acc[5]) << 16);
  o.w = (unsigned)f2bf(acc[6]) | ((unsigned)f2bf(acc[7]) << 16);
  out[slab + (size_t)node * 4 + c] = o;   // coalesced: 1KB contiguous per wave
}

// MFMA GEMM: h = bias + [xbu|fwdb|bwdb][v,:] @ (W_hi + W_lo)
// A operands quarter-major [4][n][4 uint4]; chunk kc uses slab kc&3.
// If outb: write bf16(relu(h)) quarter-major (next layer's xbu). Else fp32 outf.
__global__ __launch_bounds__(256) void k_gemm(const unsigned* __restrict__ xbu,
                                              const unsigned* __restrict__ fwdb,
                                              const unsigned* __restrict__ bwdb,
                                              const unsigned* __restrict__ Wth,
                                              const unsigned* __restrict__ Wtl,
                                              const float* __restrict__ bias,
                                              unsigned short* __restrict__ outb,
                                              float* __restrict__ outf, int n) {
  __shared__ uint4 sA[512];    // 8 KB: A chunk, frag order [mt][q][m]
  __shared__ uint4 sWh[512];   // 8 KB
  __shared__ uint4 sWl[512];   // 8 KB
  int tid = threadIdx.x;
  int bm0 = blockIdx.x * 128;
  int w = tid >> 6, lane = tid & 63;
  size_t n4 = (size_t)n * 4;

  f32x4 acc[2][8];
#pragma unroll
  for (int mt = 0; mt < 2; ++mt)
#pragma unroll
    for (int nt = 0; nt < 8; ++nt) acc[mt][nt] = (f32x4){0.f, 0.f, 0.f, 0.f};

  const uint4* Wh4 = (const uint4*)Wth;   // row j: 48 uint4 (384 bf16)
  const uint4* Wl4 = (const uint4*)Wtl;

  for (int kc = 0; kc < 12; ++kc) {
    const uint4* src4 = (const uint4*)((kc < 4) ? xbu : ((kc < 8) ? fwdb : bwdb));
    size_t slab = (size_t)(kc & 3) * n4;
    __syncthreads();
#pragma unroll
    for (int p = 0; p < 2; ++p) {
      int f = tid + p * 256;          // 0..511
      int r = f >> 2, q = f & 3;      // r: row/col-of-W, q: uint4 in slab row
      int slot = (r >> 4) * 64 + q * 16 + (r & 15);
      int v = bm0 + r;
      uint4 val = make_uint4(0u, 0u, 0u, 0u);
      if (v < n) val = src4[slab + (size_t)v * 4 + q];
      sA[slot] = val;
      sWh[slot] = Wh4[(size_t)r * 48 + kc * 4 + q];
      sWl[slot] = Wl4[(size_t)r * 48 + kc * 4 + q];
    }
    __syncthreads();
    bf16x8 a0 = ((const bf16x8*)sA)[(2 * w) * 64 + lane];
    bf16x8 a1 = ((const bf16x8*)sA)[(2 * w + 1) * 64 + lane];
#pragma unroll
    for (int nt = 0; nt < 8; ++nt) {
      bf16x8 bh = ((const bf16x8*)sWh)[nt * 64 + lane];
      bf16x8 bl = ((const bf16x8*)sWl)[nt * 64 + lane];
      acc[0][nt] = __builtin_amdgcn_mfma_f32_16x16x32_bf16(a0, bh, acc[0][nt], 0, 0, 0);
      acc[0][nt] = __builtin_amdgcn_mfma_f32_16x16x32_bf16(a0, bl, acc[0][nt], 0, 0, 0);
      acc[1][nt] = __builtin_amdgcn_mfma_f32_16x16x32_bf16(a1, bh, acc[1][nt], 0, 0, 0);
      acc[1][nt] = __builtin_amdgcn_mfma_f32_16x16x32_bf16(a1, bl, acc[1][nt], 0, 0, 0);
    }
  }

  // Epilogue. C layout: col = lane&15, row = (lane>>4)*4 + reg  (m89-verified)
  int col = lane & 15;
  float bv[8];
#pragma unroll
  for (int nt = 0; nt < 8; ++nt) bv[nt] = bias[nt * 16 + col];
#pragma unroll
  for (int mt = 0; mt < 2; ++mt) {
    int rowbase = bm0 + w * 32 + mt * 16 + (lane >> 4) * 4;
#pragma unroll
    for (int reg = 0; reg < 4; ++reg) {
      int row = rowbase + reg;
      if (row >= n) continue;
      if (outb) {
        // quarter-major bf16: element j = nt*16+col; quarter = nt>>1
#pragma unroll
        for (int nt = 0; nt < 8; ++nt) {
          float t = fmaxf(acc[mt][nt][reg] + bv[nt], 0.f);   // relu layers
          size_t addr = (size_t)(nt >> 1) * n * 32 + (size_t)row * 32 +
                        (nt & 1) * 16 + col;
          outb[addr] = f2bf(t);
        }
      } else {
#pragma unroll
        for (int nt = 0; nt < 8; ++nt) {
          float t = acc[mt][nt][reg] + bv[nt];
          outf[(size_t)row * 128 + nt * 16 + col] = t;
        }
      }
    }
  }
}

extern "C" void kernel_launch(void* const* d_in, const int* in_sizes, int n_in,
                              void* d_out, int out_size, void* d_ws, size_t ws_size,
                              hipStream_t stream) {
  const int D = 128;
  const int N = in_sizes[0] / D;
  const int E = in_sizes[7];

  const float* x  = (const float*)d_in[0];
  const float* W0 = (const float*)d_in[1];
  const float* b0 = (const float*)d_in[2];
  const float* W1 = (const float*)d_in[3];
  const float* b1 = (const float*)d_in[4];
  const float* W2 = (const float*)d_in[5];
  const float* b2 = (const float*)d_in[6];
  const int* src  = (const int*)d_in[7];
  const int* dst  = (const int*)d_in[8];
  float* out = (float*)d_out;

  char* p = (char*)d_ws;
  auto alloc = [&](size_t bytes) -> char* {
    char* r = p;
    p += (bytes + 15) & ~(size_t)15;
    return r;
  };
  float* invout = (float*)alloc((size_t)N * 4);
  float* invin  = (float*)alloc((size_t)N * 4);
  int* cntin  = (int*)alloc((size_t)N * 4);
  int* cntout = (int*)alloc((size_t)N * 4);
  int* offf = (int*)alloc((size_t)(N + 1) * 4);
  int* offb = (int*)alloc((size_t)(N + 1) * 4);
  int* rankf = (int*)alloc((size_t)E * 4);
  int* rankb = (int*)alloc((size_t)E * 4);
  uint2* epf = (uint2*)alloc((size_t)E * 8);   // (u, inv[u]) fused payload
  uint2* epb = (uint2*)alloc((size_t)E * 8);
  unsigned* xbu = (unsigned*)alloc((size_t)N * 64 * 4);   // quarter-major bf16x2
  unsigned* fwdb = (unsigned*)alloc((size_t)N * 64 * 4);
  unsigned* bwdb = (unsigned*)alloc((size_t)N * 64 * 4);
  unsigned* Wth[3], *Wtl[3];
  for (int l = 0; l < 3; ++l) {
    Wth[l] = (unsigned*)alloc((size_t)128 * 192 * 4);
    Wtl[l] = (unsigned*)alloc((size_t)128 * 192 * 4);
  }
  int nbScan = (N + 1 + 2047) / 2048;
  int* partA = (int*)alloc((size_t)(nbScan + 1) * 4);
  int* partB = (int*)alloc((size_t)(nbScan + 1) * 4);

  hipMemsetAsync(cntin, 0, (size_t)2 * N * 4, stream);  // cntin+cntout contiguous

  k_degrees<<<(E + 255) / 256, 256, 0, stream>>>(src, dst, cntin, cntout, rankf,
                                                 rankb, E);
  k_inv<<<(N + 255) / 256, 256, 0, stream>>>(cntin, cntout, invin, invout, N);
  k_scan_part<<<dim3(nbScan, 2), 256, 0, stream>>>(cntin, cntout, partA, partB, N);
  k_scan_tops<<<dim3(1, 2), 64, 0, stream>>>(partA, partB, nbScan);
  k_scan_out<<<dim3(nbScan, 2), 256, 0, stream>>>(cntin, cntout, partA, partB,
                                                  offf, offb, N);
  k_fill<<<(E + 255) / 256, 256, 0, stream>>>(src, dst, offf, offb, rankf, rankb,
                                              invout, invin, epf, epb, E);
  k_wconv3<<<dim3((128 * 192 + 255) / 256, 3), 256, 0, stream>>>(
      W0, W1, W2, Wth[0], Wth[1], Wth[2], Wtl[0], Wtl[1], Wtl[2]);

  const float* bs[3] = {b0, b1, b2};
  int aggBlocks = (N + 63) / 64;          // 64 nodes/block; dir=y, quarter=z
  int convBlocks = (N * 32 + 255) / 256;
  int gemmBlocks = (N + 127) / 128;

  k_conv<<<convBlocks, 256, 0, stream>>>(x, xbu, N);   // layer-0 input only
  for (int l = 0; l < 3; ++l) {
    k_agg5<<<dim3(aggBlocks, 2, 4), 256, 0, stream>>>(
        (const uint4*)xbu, offf, epf, offb, epb,
        (uint4*)fwdb, (uint4*)bwdb, N);
    if (l < 2) {
      k_gemm<<<gemmBlocks, 256, 0, stream>>>(xbu, fwdb, bwdb, Wth[l], Wtl[l],
                                             bs[l], (unsigned short*)xbu, nullptr, N);
    } else {
      k_gemm<<<gemmBlocks, 256, 0, stream>>>(xbu, fwdb, bwdb, Wth[l], Wtl[l],
                                             bs[l], nullptr, out, N);
    }
  }
}

// Round 9
// 486.488 us; speedup vs baseline: 1.5473x; 1.1590x over previous
//
#include <hip/hip_runtime.h>
#include <cstdint>

// ---------------------------------------------------------------------------
// DirGraphSAGE round 9:
//  - k_agg6: SINGLE-PASS row-major agg (quartering abandoned: agg is L2-miss
//    BW-bound at ~2.9TB/s; multi-pass multiplies ep/off traffic and mixes
//    slabs). 16 lanes/node, 4 nodes/wave: no shuffles, private accumulators,
//    fused (u,inv) payload, unroll x2.
//  - k_degrees: counters padded to 64B stride (1 counter/line) to kill false
//    line serialization of the 1.6M random atomics; k_inv compacts for scan.
//  - row-major bf16 xbu/fwdb/bwdb everywhere (r4 indexing).
//  - split-W MFMA GEMM + bf16 relu chaining unchanged.
// ---------------------------------------------------------------------------

typedef __bf16 bf16x8 __attribute__((ext_vector_type(8)));
typedef float f32x4 __attribute__((ext_vector_type(4)));

__device__ __forceinline__ unsigned short f2bf(float f) {
  unsigned u = __float_as_uint(f);
  u += 0x7FFFu + ((u >> 16) & 1u);   // round-to-nearest-even
  return (unsigned short)(u >> 16);
}
__device__ __forceinline__ float bflo(unsigned u) { return __uint_as_float(u << 16); }
__device__ __forceinline__ float bfhi(unsigned u) { return __uint_as_float(u & 0xFFFF0000u); }

// Padded counters: one 4B counter per 64B line (stride 16 ints).
__global__ __launch_bounds__(256) void k_degrees(const int* __restrict__ src,
                                                 const int* __restrict__ dst,
                                                 int* __restrict__ cin_p,
                                                 int* __restrict__ cout_p,
                                                 int* __restrict__ rankf,
                                                 int* __restrict__ rankb, int E) {
  int e = blockIdx.x * 256 + threadIdx.x;
  if (e >= E) return;
  int s = src[e], d = dst[e];
  rankf[e] = atomicAdd(&cin_p[(size_t)d * 16], 1);   // rank in fwd list (by dst)
  rankb[e] = atomicAdd(&cout_p[(size_t)s * 16], 1);  // rank in bwd list (by src)
}

// Reads padded counters; writes inv factors AND dense counts for the scan.
__global__ __launch_bounds__(256) void k_inv(const int* __restrict__ cin_p,
                                             const int* __restrict__ cout_p,
                                             float* __restrict__ inv_in,
                                             float* __restrict__ inv_out,
                                             int* __restrict__ cin_d,
                                             int* __restrict__ cout_d, int n) {
  int i = blockIdx.x * 256 + threadIdx.x;
  if (i >= n) return;
  int ci = cin_p[(size_t)i * 16], co = cout_p[(size_t)i * 16];
  inv_in[i]  = 1.0f / (float)max(ci, 1);
  inv_out[i] = 1.0f / (float)max(co, 1);
  cin_d[i] = ci;
  cout_d[i] = co;
}

// --- 3-phase multi-block exclusive scan (CHUNK=2048/block, y-dim = which array)
__global__ __launch_bounds__(256) void k_scan_part(const int* __restrict__ cntA,
                                                   const int* __restrict__ cntB,
                                                   int* __restrict__ partA,
                                                   int* __restrict__ partB, int n) {
  const int* cnt = blockIdx.y ? cntB : cntA;
  int* part = blockIdx.y ? partB : partA;
  __shared__ int red[256];
  int t = threadIdx.x;
  int base = blockIdx.x * 2048 + t * 8;
  int s = 0;
#pragma unroll
  for (int i = 0; i < 8; ++i) {
    int idx = base + i;
    if (idx < n) s += cnt[idx];
  }
  red[t] = s;
  __syncthreads();
  for (int o = 128; o > 0; o >>= 1) {
    if (t < o) red[t] += red[t + o];
    __syncthreads();
  }
  if (t == 0) part[blockIdx.x] = red[0];
}

__global__ __launch_bounds__(64) void k_scan_tops(int* __restrict__ partA,
                                                  int* __restrict__ partB, int nb) {
  int* part = blockIdx.y ? partB : partA;
  if (threadIdx.x == 0) {
    int run = 0;
    for (int i = 0; i < nb; ++i) { int v = part[i]; part[i] = run; run += v; }
  }
}

__global__ __launch_bounds__(256) void k_scan_out(const int* __restrict__ cntA,
                                                  const int* __restrict__ cntB,
                                                  const int* __restrict__ partA,
                                                  const int* __restrict__ partB,
                                                  int* __restrict__ offA,
                                                  int* __restrict__ offB, int n) {
  const int* cnt = blockIdx.y ? cntB : cntA;
  const int* part = blockIdx.y ? partB : partA;
  int* off = blockIdx.y ? offB : offA;
  __shared__ int ts[256];
  int t = threadIdx.x;
  int base = blockIdx.x * 2048 + t * 8;
  int v[8];
  int s = 0;
#pragma unroll
  for (int i = 0; i < 8; ++i) {
    int idx = base + i;
    int c = (idx < n) ? cnt[idx] : 0;
    v[i] = s;          // exclusive prefix within thread
    s += c;
  }
  ts[t] = s;
  __syncthreads();
  for (int o = 1; o < 256; o <<= 1) {
    int val = (t >= o) ? ts[t - o] : 0;
    __syncthreads();
    ts[t] += val;
    __syncthreads();
  }
  int blockbase = part[blockIdx.x] + (t ? ts[t - 1] : 0);
#pragma unroll
  for (int i = 0; i < 8; ++i) {
    int idx = base + i;
    if (idx <= n) off[idx] = blockbase + v[i];   // idx==n writes the total
  }
}

// Atomic-free fill; writes fused edge payload (u, inv[u]).
__global__ __launch_bounds__(256) void k_fill(const int* __restrict__ src,
                                              const int* __restrict__ dst,
                                              const int* __restrict__ offf,
                                              const int* __restrict__ offb,
                                              const int* __restrict__ rankf,
                                              const int* __restrict__ rankb,
                                              const float* __restrict__ invout,
                                              const float* __restrict__ invin,
                                              uint2* __restrict__ epf,
                                              uint2* __restrict__ epb, int E) {
  int e = blockIdx.x * 256 + threadIdx.x;
  if (e >= E) return;
  int s = src[e], d = dst[e];
  epf[offf[d] + rankf[e]] = make_uint2((unsigned)s, __float_as_uint(invout[s]));
  epb[offb[s] + rankb[e]] = make_uint2((unsigned)d, __float_as_uint(invin[d]));
}

// x (fp32, N x 128) -> xbu row-major packed bf16x2 (32 uint2 per row)
__global__ __launch_bounds__(256) void k_conv(const float* __restrict__ x,
                                              unsigned* __restrict__ xbu, int n) {
  int idx = blockIdx.x * 256 + threadIdx.x;  // over n*32 float4s
  if (idx >= n * 32) return;
  float4 xv = ((const float4*)x)[idx];
  unsigned u0 = (unsigned)f2bf(xv.x) | ((unsigned)f2bf(xv.y) << 16);
  unsigned u1 = (unsigned)f2bf(xv.z) | ((unsigned)f2bf(xv.w) << 16);
  ((uint2*)xbu)[idx] = make_uint2(u0, u1);
}

// W (fp32 384x128) -> Wt_hi, Wt_lo (bf16, 128x384, transposed, packed x2)
__global__ __launch_bounds__(256) void k_wconv3(
    const float* __restrict__ Wa, const float* __restrict__ Wb,
    const float* __restrict__ Wc,
    unsigned* __restrict__ Ha, unsigned* __restrict__ Hb, unsigned* __restrict__ Hc,
    unsigned* __restrict__ La, unsigned* __restrict__ Lb, unsigned* __restrict__ Lc) {
  const float* W = (blockIdx.y == 0) ? Wa : ((blockIdx.y == 1) ? Wb : Wc);
  unsigned* Wth = (blockIdx.y == 0) ? Ha : ((blockIdx.y == 1) ? Hb : Hc);
  unsigned* Wtl = (blockIdx.y == 0) ? La : ((blockIdx.y == 1) ? Lb : Lc);
  int t = blockIdx.x * 256 + threadIdx.x;   // 128*192 threads; t = j*192 + k2
  if (t >= 128 * 192) return;
  int j = t / 192, k2 = t - j * 192;
  int k = k2 * 2;
  float w0 = W[k * 128 + j], w1 = W[(k + 1) * 128 + j];
  unsigned short h0 = f2bf(w0), h1 = f2bf(w1);
  float l0 = w0 - __uint_as_float((unsigned)h0 << 16);
  float l1 = w1 - __uint_as_float((unsigned)h1 << 16);
  Wth[t] = (unsigned)h0 | ((unsigned)h1 << 16);
  Wtl[t] = (unsigned)f2bf(l0) | ((unsigned)f2bf(l1) << 16);
}

// Single-pass row-major aggregation. 16 lanes/node (uint4 col c), 4 nodes/wave.
// grid: x = node blocks (16 nodes/block), y = dir. No shuffles; coalesced
// 1KB/wave store. Unroll x2 for two independent gather chains.
__global__ __launch_bounds__(256) void k_agg6(const uint4* __restrict__ xb,
                                              const int* __restrict__ offA,
                                              const uint2* __restrict__ epA,
                                              const int* __restrict__ offB,
                                              const uint2* __restrict__ epB,
                                              uint4* __restrict__ outA,
                                              uint4* __restrict__ outB, int n) {
  int lane = threadIdx.x & 63;
  int gi = lane >> 4, c = lane & 15;     // node-in-wave, uint4 column
  int node = ((blockIdx.x * 256 + threadIdx.x) >> 6) * 4 + gi;
  if (node >= n) return;
  const int* off = blockIdx.y ? offB : offA;
  const uint2* ep = blockIdx.y ? epB : epA;
  uint4* out = blockIdx.y ? outB : outA;

  int i = off[node], end = off[node + 1];
  float acc[8];
#pragma unroll
  for (int k = 0; k < 8; ++k) acc[k] = 0.f;

  for (; i + 1 < end; i += 2) {
    uint2 e0 = ep[i], e1 = ep[i + 1];
    uint4 r0 = xb[(size_t)e0.x * 16 + c];
    uint4 r1 = xb[(size_t)e1.x * 16 + c];
    float w0 = __uint_as_float(e0.y), w1 = __uint_as_float(e1.y);
    acc[0] = fmaf(bflo(r0.x), w0, acc[0]); acc[1] = fmaf(bfhi(r0.x), w0, acc[1]);
    acc[2] = fmaf(bflo(r0.y), w0, acc[2]); acc[3] = fmaf(bfhi(r0.y), w0, acc[3]);
    acc[4] = fmaf(bflo(r0.z), w0, acc[4]); acc[5] = fmaf(bfhi(r0.z), w0, acc[5]);
    acc[6] = fmaf(bflo(r0.w), w0, acc[6]); acc[7] = fmaf(bfhi(r0.w), w0, acc[7]);
    acc[0] = fmaf(bflo(r1.x), w1, acc[0]); acc[1] = fmaf(bfhi(r1.x), w1, acc[1]);
    acc[2] = fmaf(bflo(r1.y), w1, acc[2]); acc[3] = fmaf(bfhi(r1.y), w1, acc[3]);
    acc[4] = fmaf(bflo(r1.z), w1, acc[4]); acc[5] = fmaf(bfhi(r1.z), w1, acc[5]);
    acc[6] = fmaf(bflo(r1.w), w1, acc[6]); acc[7] = fmaf(bfhi(r1.w), w1, acc[7]);
  }
  if (i < end) {
    uint2 e0 = ep[i];
    uint4 r0 = xb[(size_t)e0.x * 16 + c];
    float w0 = __uint_as_float(e0.y);
    acc[0] = fmaf(bflo(r0.x), w0, acc[0]); acc[1] = fmaf(bfhi(r0.x), w0, acc[1]);
    acc[2] = fmaf(bflo(r0.y), w0, acc[2]); acc[3] = fmaf(bfhi(r0.y), w0, acc[3]);
    acc[4] = fmaf(bflo(r0.z), w0, acc[4]); acc[5] = fmaf(bfhi(r0.z), w0, acc[5]);
    acc[6] = fmaf(bflo(r0.w), w0, acc[6]); acc[7] = fmaf(bfhi(r0.w), w0, acc[7]);
  }

  uint4 o;
  o.x = (unsigned)f2bf(acc[0]) | ((unsigned)f2bf(acc[1]) << 16);
  o.y = (unsigned)f2bf(acc[2]) | ((unsigned)f2bf(acc[3]) << 16);
  o.z = (unsigned)f2bf(acc[4]) | ((unsigned)f2bf(acc[5]) << 16);
  o.w = (unsigned)f2bf(acc[6]) | ((unsigned)f2bf(acc[7]) << 16);
  out[(size_t)node * 16 + c] = o;
}

// MFMA GEMM: h = bias + [xbu|fwdb|bwdb][v,:] @ (W_hi + W_lo)   (row-major A)
// If outb: write bf16(relu(h)) row-major (next layer's xbu). Else fp32 outf.
__global__ __launch_bounds__(256) void k_gemm(const unsigned* __restrict__ xbu,
                                              const unsigned* __restrict__ fwdb,
                                              const unsigned* __restrict__ bwdb,
                                              const unsigned* __restrict__ Wth,
                                              const unsigned* __restrict__ Wtl,
                                              const float* __restrict__ bias,
                                              unsigned short* __restrict__ outb,
                                              float* __restrict__ outf, int n) {
  __shared__ uint4 sA[512];    // 8 KB: A chunk, frag order [mt][q][m]
  __shared__ uint4 sWh[512];   // 8 KB
  __shared__ uint4 sWl[512];   // 8 KB
  int tid = threadIdx.x;
  int bm0 = blockIdx.x * 128;
  int w = tid >> 6, lane = tid & 63;

  f32x4 acc[2][8];
#pragma unroll
  for (int mt = 0; mt < 2; ++mt)
#pragma unroll
    for (int nt = 0; nt < 8; ++nt) acc[mt][nt] = (f32x4){0.f, 0.f, 0.f, 0.f};

  const uint4* Wh4 = (const uint4*)Wth;   // row j: 48 uint4 (384 bf16)
  const uint4* Wl4 = (const uint4*)Wtl;

  for (int kc = 0; kc < 12; ++kc) {
    const uint4* src4 = (const uint4*)((kc < 4) ? xbu : ((kc < 8) ? fwdb : bwdb));
    int ko = (kc & 3) * 4;   // uint4 offset within row (16 uint4 = 128 bf16)
    __syncthreads();
#pragma unroll
    for (int p = 0; p < 2; ++p) {
      int f = tid + p * 256;          // 0..511
      int r = f >> 2, q = f & 3;      // r: row/col-of-W, q: k-quad
      int slot = (r >> 4) * 64 + q * 16 + (r & 15);
      int v = bm0 + r;
      uint4 val = make_uint4(0u, 0u, 0u, 0u);
      if (v < n) val = src4[(size_t)v * 16 + ko + q];
      sA[slot] = val;
      sWh[slot] = Wh4[(size_t)r * 48 + kc * 4 + q];
      sWl[slot] = Wl4[(size_t)r * 48 + kc * 4 + q];
    }
    __syncthreads();
    bf16x8 a0 = ((const bf16x8*)sA)[(2 * w) * 64 + lane];
    bf16x8 a1 = ((const bf16x8*)sA)[(2 * w + 1) * 64 + lane];
#pragma unroll
    for (int nt = 0; nt < 8; ++nt) {
      bf16x8 bh = ((const bf16x8*)sWh)[nt * 64 + lane];
      bf16x8 bl = ((const bf16x8*)sWl)[nt * 64 + lane];
      acc[0][nt] = __builtin_amdgcn_mfma_f32_16x16x32_bf16(a0, bh, acc[0][nt], 0, 0, 0);
      acc[0][nt] = __builtin_amdgcn_mfma_f32_16x16x32_bf16(a0, bl, acc[0][nt], 0, 0, 0);
      acc[1][nt] = __builtin_amdgcn_mfma_f32_16x16x32_bf16(a1, bh, acc[1][nt], 0, 0, 0);
      acc[1][nt] = __builtin_amdgcn_mfma_f32_16x16x32_bf16(a1, bl, acc[1][nt], 0, 0, 0);
    }
  }

  // Epilogue. C layout: col = lane&15, row = (lane>>4)*4 + reg  (m89-verified)
  int col = lane & 15;
  float bv[8];
#pragma unroll
  for (int nt = 0; nt < 8; ++nt) bv[nt] = bias[nt * 16 + col];
#pragma unroll
  for (int mt = 0; mt < 2; ++mt) {
    int rowbase = bm0 + w * 32 + mt * 16 + (lane >> 4) * 4;
#pragma unroll
    for (int reg = 0; reg < 4; ++reg) {
      int row = rowbase + reg;
      if (row >= n) continue;
      if (outb) {
#pragma unroll
        for (int nt = 0; nt < 8; ++nt) {
          float t = fmaxf(acc[mt][nt][reg] + bv[nt], 0.f);   // relu layers
          outb[(size_t)row * 128 + nt * 16 + col] = f2bf(t);
        }
      } else {
#pragma unroll
        for (int nt = 0; nt < 8; ++nt) {
          float t = acc[mt][nt][reg] + bv[nt];
          outf[(size_t)row * 128 + nt * 16 + col] = t;
        }
      }
    }
  }
}

extern "C" void kernel_launch(void* const* d_in, const int* in_sizes, int n_in,
                              void* d_out, int out_size, void* d_ws, size_t ws_size,
                              hipStream_t stream) {
  const int D = 128;
  const int N = in_sizes[0] / D;
  const int E = in_sizes[7];

  const float* x  = (const float*)d_in[0];
  const float* W0 = (const float*)d_in[1];
  const float* b0 = (const float*)d_in[2];
  const float* W1 = (const float*)d_in[3];
  const float* b1 = (const float*)d_in[4];
  const float* W2 = (const float*)d_in[5];
  const float* b2 = (const float*)d_in[6];
  const int* src  = (const int*)d_in[7];
  const int* dst  = (const int*)d_in[8];
  float* out = (float*)d_out;

  char* p = (char*)d_ws;
  auto alloc = [&](size_t bytes) -> char* {
    char* r = p;
    p += (bytes + 15) & ~(size_t)15;
    return r;
  };
  float* invout = (float*)alloc((size_t)N * 4);
  float* invin  = (float*)alloc((size_t)N * 4);
  int* cin_p  = (int*)alloc((size_t)N * 64);   // padded: 1 counter / 64B line
  int* cout_p = (int*)alloc((size_t)N * 64);
  int* cin_d  = (int*)alloc((size_t)N * 4);    // dense for scan
  int* cout_d = (int*)alloc((size_t)N * 4);
  int* offf = (int*)alloc((size_t)(N + 1) * 4);
  int* offb = (int*)alloc((size_t)(N + 1) * 4);
  int* rankf = (int*)alloc((size_t)E * 4);
  int* rankb = (int*)alloc((size_t)E * 4);
  uint2* epf = (uint2*)alloc((size_t)E * 8);   // (u, inv[u]) fused payload
  uint2* epb = (uint2*)alloc((size_t)E * 8);
  unsigned* xbu = (unsigned*)alloc((size_t)N * 64 * 4);   // row-major bf16x2
  unsigned* fwdb = (unsigned*)alloc((size_t)N * 64 * 4);
  unsigned* bwdb = (unsigned*)alloc((size_t)N * 64 * 4);
  unsigned* Wth[3], *Wtl[3];
  for (int l = 0; l < 3; ++l) {
    Wth[l] = (unsigned*)alloc((size_t)128 * 192 * 4);
    Wtl[l] = (unsigned*)alloc((size_t)128 * 192 * 4);
  }
  int nbScan = (N + 1 + 2047) / 2048;
  int* partA = (int*)alloc((size_t)(nbScan + 1) * 4);
  int* partB = (int*)alloc((size_t)(nbScan + 1) * 4);

  hipMemsetAsync(cin_p, 0, (size_t)2 * N * 64, stream);  // cin_p+cout_p contiguous

  k_degrees<<<(E + 255) / 256, 256, 0, stream>>>(src, dst, cin_p, cout_p, rankf,
                                                 rankb, E);
  k_inv<<<(N + 255) / 256, 256, 0, stream>>>(cin_p, cout_p, invin, invout,
                                             cin_d, cout_d, N);
  k_scan_part<<<dim3(nbScan, 2), 256, 0, stream>>>(cin_d, cout_d, partA, partB, N);
  k_scan_tops<<<dim3(1, 2), 64, 0, stream>>>(partA, partB, nbScan);
  k_scan_out<<<dim3(nbScan, 2), 256, 0, stream>>>(cin_d, cout_d, partA, partB,
                                                  offf, offb, N);
  k_fill<<<(E + 255) / 256, 256, 0, stream>>>(src, dst, offf, offb, rankf, rankb,
                                              invout, invin, epf, epb, E);
  k_wconv3<<<dim3((128 * 192 + 255) / 256, 3), 256, 0, stream>>>(
      W0, W1, W2, Wth[0], Wth[1], Wth[2], Wtl[0], Wtl[1], Wtl[2]);

  const float* bs[3] = {b0, b1, b2};
  int aggBlocks = (N + 15) / 16;          // 16 nodes/block (4 waves); dir = y
  int convBlocks = (N * 32 + 255) / 256;
  int gemmBlocks = (N + 127) / 128;

  k_conv<<<convBlocks, 256, 0, stream>>>(x, xbu, N);   // layer-0 input only
  for (int l = 0; l < 3; ++l) {
    k_agg6<<<dim3(aggBlocks, 2), 256, 0, stream>>>(
        (const uint4*)xbu, offf, epf, offb, epb,
        (uint4*)fwdb, (uint4*)bwdb, N);
    if (l < 2) {
      k_gemm<<<gemmBlocks, 256, 0, stream>>>(xbu, fwdb, bwdb, Wth[l], Wtl[l],
                                             bs[l], (unsigned short*)xbu, nullptr, N);
    } else {
      k_gemm<<<gemmBlocks, 256, 0, stream>>>(xbu, fwdb, bwdb, Wth[l], Wtl[l],
                                             bs[l], nullptr, out, N);
    }
  }
}